// Round 14
// baseline (249.575 us; speedup 1.0000x reference)
//
#include <hip/hip_runtime.h>
#include <cstddef>

#define MAXB 512      // max coarse buckets (N<=65536 at 128 nodes/bucket)
#define BSHIFT 7      // 128 dst nodes per bucket
#define ACHUNK 8192   // edges per passA/histA block

typedef __attribute__((ext_vector_type(8))) short short8;
typedef __attribute__((ext_vector_type(4))) float f32x4;

// ---- bf16 pack/unpack helpers (RNE) ----
__device__ inline unsigned pack_bf16x2(float a, float b) {
    unsigned ua = __float_as_uint(a), ub = __float_as_uint(b);
    ua = (ua + 0x7FFFu + ((ua >> 16) & 1u)) >> 16;
    ub = (ub + 0x7FFFu + ((ub >> 16) & 1u)) >> 16;
    return ua | (ub << 16);
}
__device__ inline unsigned short bf16rne(float f) {
    unsigned u = __float_as_uint(f);
    return (unsigned short)((u + 0x7FFFu + ((u >> 16) & 1u)) >> 16);
}
__device__ inline float bf_lo(unsigned u) { return __uint_as_float(u << 16); }
__device__ inline float bf_hi(unsigned u) { return __uint_as_float(u & 0xFFFF0000u); }

__device__ inline void nt_store4(const float4& v, float* p) {
    f32x4 t = { v.x, v.y, v.z, v.w };
    __builtin_nontemporal_store(t, (f32x4*)p);
}

// ---------------- zero the bucket-count table ----------------
__global__ __launch_bounds__(512) void k_zero512(int* __restrict__ p) {
    p[threadIdx.x] = 0;
}

// ---------------- histA: global per-bucket edge counts ----------------
__global__ __launch_bounds__(256) void k_histA(const int* __restrict__ dst, int* __restrict__ bcnt,
                                               int E, int nbuck) {
    __shared__ int hist[MAXB];
    const int tid = threadIdx.x;
    const int e0  = blockIdx.x * ACHUNK;
    const int e1  = min(e0 + ACHUNK, E);
    for (int i = tid; i < nbuck; i += 256) hist[i] = 0;
    __syncthreads();
    for (int e = e0 + tid; e < e1; e += 256)
        atomicAdd(&hist[dst[e] >> BSHIFT], 1);
    __syncthreads();
    for (int i = tid; i < nbuck; i += 256)
        if (hist[i]) atomicAdd(&bcnt[i], hist[i]);
}

// ---------------- bscan: exclusive scan of bcnt -> bstart; bcur = bstart ----------------
__global__ __launch_bounds__(512) void k_bscan(const int* __restrict__ bcnt, int* __restrict__ bstart,
                                               int* __restrict__ bcur) {
    __shared__ int sh[512];
    const int t = threadIdx.x;
    int v = bcnt[t];
    sh[t] = v;
    __syncthreads();
    for (int d = 1; d < 512; d <<= 1) {
        int u = (t >= d) ? sh[t - d] : 0;
        __syncthreads();
        sh[t] += u;
        __syncthreads();
    }
    int ex = sh[t] - v;
    bstart[t] = ex;
    bcur[t]   = ex;
}

// ---------------- pass A: coarse split into bucket runs (block-owned reservations) ----------------
__global__ __launch_bounds__(256) void k_passA(const int* __restrict__ src, const int* __restrict__ dst,
                                               int* __restrict__ bcur, int2* __restrict__ tmp,
                                               int E, int nbuck) {
    __shared__ int hist[MAXB];
    __shared__ int gbase[MAXB];
    const int tid = threadIdx.x;
    const int e0  = blockIdx.x * ACHUNK;
    const int e1  = min(e0 + ACHUNK, E);
    for (int i = tid; i < nbuck; i += 256) hist[i] = 0;
    __syncthreads();
    for (int e = e0 + tid; e < e1; e += 256)
        atomicAdd(&hist[dst[e] >> BSHIFT], 1);
    __syncthreads();
    for (int i = tid; i < nbuck; i += 256) {
        int c = hist[i];
        gbase[i] = c ? atomicAdd(&bcur[i], c) : 0;
        hist[i] = 0;                       // reuse as local cursor
    }
    __syncthreads();
    for (int e = e0 + tid; e < e1; e += 256) {
        int d = dst[e];
        int b = d >> BSHIFT;
        int slot = atomicAdd(&hist[b], 1);
        tmp[gbase[b] + slot] = make_int2(src[e], d);
    }
}

// ---------------- pass B: derive deg/dinv/off + exact placement ----------------
__global__ __launch_bounds__(256) void k_passB(const int2* __restrict__ tmp, const int* __restrict__ bstart,
                                               const int* __restrict__ bcnt, int* __restrict__ deg,
                                               float* __restrict__ dinv, int* __restrict__ off,
                                               int* __restrict__ esrc, int N) {
    __shared__ int cnt[1 << BSHIFT];
    __shared__ int loff[1 << BSHIFT];
    __shared__ int cur[1 << BSHIFT];
    const int b     = blockIdx.x;
    const int tid   = threadIdx.x;
    const int node0 = b << BSHIFT;
    const int base  = bstart[b];
    const int cntB  = bcnt[b];

    if (tid < 128) cnt[tid] = 0;
    __syncthreads();
    for (int i = tid; i < cntB; i += 256)
        atomicAdd(&cnt[tmp[base + i].y - node0], 1);
    __syncthreads();
    if (tid < 128) loff[tid] = cnt[tid];
    __syncthreads();
    for (int d = 1; d < 128; d <<= 1) {
        int u = (tid >= d && tid < 128) ? loff[tid - d] : 0;
        __syncthreads();
        if (tid < 128) loff[tid] += u;
        __syncthreads();
    }
    if (tid < 128) {
        int c  = cnt[tid];
        int ex = loff[tid] - c;            // exclusive scan
        cur[tid] = ex;
        if (node0 + tid < N) {
            deg [node0 + tid] = c + 1;     // +1 self-loop
            dinv[node0 + tid] = rsqrtf((float)(c + 1));
            off [node0 + tid] = base + ex;
        }
    }
    __syncthreads();
    for (int i = tid; i < cntB; i += 256) {
        int2 ent = tmp[base + i];
        int  pos = atomicAdd(&cur[ent.y - node0], 1);
        esrc[base + pos] = ent.x;
    }
}

// ---------------- GEMM1 (MFMA): xwbA/xwbB [M,64](bf16) = x[M,128] @ W[128,128] ----------------
__global__ __launch_bounds__(256) void k_gemm1(const float* __restrict__ x, const float* __restrict__ W,
                                               unsigned short* __restrict__ xwbA,
                                               unsigned short* __restrict__ xwbB, int M) {
    __shared__ unsigned short Wt[128 * 144];
    __shared__ unsigned short outS[64 * 128];
    const int tid  = threadIdx.x;
    const int row0 = blockIdx.x * 64;

    for (int i = tid; i < 128 * 128; i += 256) {
        int k = i >> 7, col = i & 127;
        Wt[col * 144 + k] = bf16rne(W[i]);
    }
    __syncthreads();

    const int w  = tid >> 6, l = tid & 63;
    const int lr = l & 15,  kg = l >> 4;
    const int row = row0 + w * 16 + lr;

    f32x4 zero4 = {0.f, 0.f, 0.f, 0.f};
    f32x4 acc[8];
#pragma unroll
    for (int ct = 0; ct < 8; ++ct) acc[ct] = zero4;

#pragma unroll
    for (int ks = 0; ks < 4; ++ks) {
        uint4 aw = make_uint4(0u, 0u, 0u, 0u);
        if (row < M) {
            const float* ap = x + (size_t)row * 128 + ks * 32 + kg * 8;
            float4 u = *(const float4*)ap;
            float4 v = *(const float4*)(ap + 4);
            aw = make_uint4(pack_bf16x2(u.x, u.y), pack_bf16x2(u.z, u.w),
                            pack_bf16x2(v.x, v.y), pack_bf16x2(v.z, v.w));
        }
        short8 afrag = *(short8*)&aw;
#pragma unroll
        for (int ct = 0; ct < 8; ++ct) {
            short8 bfrag = *(const short8*)&Wt[(ct * 16 + lr) * 144 + ks * 32 + kg * 8];
            acc[ct] = __builtin_amdgcn_mfma_f32_16x16x32_bf16(afrag, bfrag, acc[ct], 0, 0, 0);
        }
    }

#pragma unroll
    for (int ct = 0; ct < 8; ++ct)
#pragma unroll
        for (int q = 0; q < 4; ++q)
            outS[(w * 16 + kg * 4 + q) * 128 + ct * 16 + lr] = bf16rne(acc[ct][q]);
    __syncthreads();

    // 64 rows x 16 uint4; first 8 -> xwbA (cols 0..63), last 8 -> xwbB (cols 64..127)
    for (int i = 0; i < 4; ++i) {
        int idx = i * 256 + tid;
        int r   = idx >> 4, q = idx & 15;
        if (row0 + r < M) {
            uint4 v = ((const uint4*)outS)[idx];
            if (q < 8) ((uint4*)xwbA)[(size_t)(row0 + r) * 8 + q]       = v;
            else       ((uint4*)xwbB)[(size_t)(row0 + r) * 8 + (q - 8)] = v;
        }
    }
}

// ---------------- GEMM2 (MFMA): hwbA/hwbB [M,32](bf16) = relu(h[M,128]) @ W[128,64] ----------------
__global__ __launch_bounds__(256) void k_gemm2(const float* __restrict__ h_in, const float* __restrict__ W,
                                               unsigned short* __restrict__ hwbA,
                                               unsigned short* __restrict__ hwbB, int M) {
    __shared__ unsigned short Wt[64 * 144];
    __shared__ unsigned short outS[64 * 64];
    const int tid  = threadIdx.x;
    const int row0 = blockIdx.x * 64;

    for (int i = tid; i < 128 * 64; i += 256) {
        int k = i >> 6, col = i & 63;
        Wt[col * 144 + k] = bf16rne(W[i]);
    }
    __syncthreads();

    const int w  = tid >> 6, l = tid & 63;
    const int lr = l & 15,  kg = l >> 4;
    const int row = row0 + w * 16 + lr;

    f32x4 zero4 = {0.f, 0.f, 0.f, 0.f};
    f32x4 acc[4];
#pragma unroll
    for (int ct = 0; ct < 4; ++ct) acc[ct] = zero4;

#pragma unroll
    for (int ks = 0; ks < 4; ++ks) {
        uint4 aw = make_uint4(0u, 0u, 0u, 0u);
        if (row < M) {
            const float* ap = h_in + (size_t)row * 128 + ks * 32 + kg * 8;
            float4 u = *(const float4*)ap;
            float4 v = *(const float4*)(ap + 4);
            u.x = fmaxf(u.x, 0.f); u.y = fmaxf(u.y, 0.f); u.z = fmaxf(u.z, 0.f); u.w = fmaxf(u.w, 0.f);
            v.x = fmaxf(v.x, 0.f); v.y = fmaxf(v.y, 0.f); v.z = fmaxf(v.z, 0.f); v.w = fmaxf(v.w, 0.f);
            aw = make_uint4(pack_bf16x2(u.x, u.y), pack_bf16x2(u.z, u.w),
                            pack_bf16x2(v.x, v.y), pack_bf16x2(v.z, v.w));
        }
        short8 afrag = *(short8*)&aw;
#pragma unroll
        for (int ct = 0; ct < 4; ++ct) {
            short8 bfrag = *(const short8*)&Wt[(ct * 16 + lr) * 144 + ks * 32 + kg * 8];
            acc[ct] = __builtin_amdgcn_mfma_f32_16x16x32_bf16(afrag, bfrag, acc[ct], 0, 0, 0);
        }
    }

#pragma unroll
    for (int ct = 0; ct < 4; ++ct)
#pragma unroll
        for (int q = 0; q < 4; ++q)
            outS[(w * 16 + kg * 4 + q) * 64 + ct * 16 + lr] = bf16rne(acc[ct][q]);
    __syncthreads();

    // 64 rows x 8 uint4; first 4 -> hwbA (cols 0..31), last 4 -> hwbB (cols 32..63)
    for (int i = 0; i < 2; ++i) {
        int idx = i * 256 + tid;
        int r   = idx >> 3, q = idx & 7;
        if (row0 + r < M) {
            uint4 v = ((const uint4*)outS)[idx];
            if (q < 4) ((uint4*)hwbA)[(size_t)(row0 + r) * 4 + q]       = v;
            else       ((uint4*)hwbB)[(size_t)(row0 + r) * 4 + (q - 4)] = v;
        }
    }
}

// ---------------- agg half, 64 cols: four 16-lane groups, 4 edges/iter, 8-deep ----------------
// tbl rows are 16 uint2 (64 bf16 cols). Writes out[node*ostride + colbase + c0].
__global__ __launch_bounds__(256) void k_aggh64(const uint2* __restrict__ tbl, const int* __restrict__ esrc,
                                                const int* __restrict__ off, const int* __restrict__ deg,
                                                const float* __restrict__ dinv, const float* __restrict__ b,
                                                float* __restrict__ out, int N, int colbase) {
    const int node = blockIdx.x * 4 + (threadIdx.x >> 6);
    if (node >= N) return;
    const int lane = threadIdx.x & 63;
    const int grp  = lane >> 4;          // 0..3
    const int lc   = lane & 15;          // uint2 index within row
    const int c0   = lc << 2;            // first of 4 cols

    const float di = dinv[node];
    float4 acc0 = {0,0,0,0}, acc1 = {0,0,0,0}, acc2 = {0,0,0,0}, acc3 = {0,0,0,0};
    if (grp == 0) {
        float w0 = di * di;
        uint2  sv = tbl[(size_t)node * 16 + lc];
        float4 bb = *(const float4*)&b[colbase + c0];
        acc0.x = bb.x + bf_lo(sv.x) * w0; acc0.y = bb.y + bf_hi(sv.x) * w0;
        acc0.z = bb.z + bf_lo(sv.y) * w0; acc0.w = bb.w + bf_hi(sv.y) * w0;
    }

    const int base = off[node];
    const int cnt  = deg[node] - 1;
    for (int p0 = 0; p0 < cnt; p0 += 64) {
        int   es = 0;
        float ew = 0.f;
        if (p0 + lane < cnt) {
            es = __builtin_nontemporal_load(&esrc[base + p0 + lane]);
            ew = dinv[es] * di;
        }
        const int take = min(64, cnt - p0);
        int j = 0;
        for (; j + 32 <= take; j += 32) {   // 8 gathers in flight per group
            int i0 = j + grp,      i1 = j + 4 + grp,  i2 = j + 8 + grp,  i3 = j + 12 + grp;
            int i4 = j + 16 + grp, i5 = j + 20 + grp, i6 = j + 24 + grp, i7 = j + 28 + grp;
            int   s0 = __shfl(es, i0); float w0f = __shfl(ew, i0);
            int   s1 = __shfl(es, i1); float w1f = __shfl(ew, i1);
            int   s2 = __shfl(es, i2); float w2f = __shfl(ew, i2);
            int   s3 = __shfl(es, i3); float w3f = __shfl(ew, i3);
            int   s4 = __shfl(es, i4); float w4f = __shfl(ew, i4);
            int   s5 = __shfl(es, i5); float w5f = __shfl(ew, i5);
            int   s6 = __shfl(es, i6); float w6f = __shfl(ew, i6);
            int   s7 = __shfl(es, i7); float w7f = __shfl(ew, i7);
            uint2 v0 = tbl[(size_t)s0 * 16 + lc];
            uint2 v1 = tbl[(size_t)s1 * 16 + lc];
            uint2 v2 = tbl[(size_t)s2 * 16 + lc];
            uint2 v3 = tbl[(size_t)s3 * 16 + lc];
            uint2 v4 = tbl[(size_t)s4 * 16 + lc];
            uint2 v5 = tbl[(size_t)s5 * 16 + lc];
            uint2 v6 = tbl[(size_t)s6 * 16 + lc];
            uint2 v7 = tbl[(size_t)s7 * 16 + lc];
            acc0.x += bf_lo(v0.x) * w0f; acc0.y += bf_hi(v0.x) * w0f;
            acc0.z += bf_lo(v0.y) * w0f; acc0.w += bf_hi(v0.y) * w0f;
            acc1.x += bf_lo(v1.x) * w1f; acc1.y += bf_hi(v1.x) * w1f;
            acc1.z += bf_lo(v1.y) * w1f; acc1.w += bf_hi(v1.y) * w1f;
            acc2.x += bf_lo(v2.x) * w2f; acc2.y += bf_hi(v2.x) * w2f;
            acc2.z += bf_lo(v2.y) * w2f; acc2.w += bf_hi(v2.y) * w2f;
            acc3.x += bf_lo(v3.x) * w3f; acc3.y += bf_hi(v3.x) * w3f;
            acc3.z += bf_lo(v3.y) * w3f; acc3.w += bf_hi(v3.y) * w3f;
            acc0.x += bf_lo(v4.x) * w4f; acc0.y += bf_hi(v4.x) * w4f;
            acc0.z += bf_lo(v4.y) * w4f; acc0.w += bf_hi(v4.y) * w4f;
            acc1.x += bf_lo(v5.x) * w5f; acc1.y += bf_hi(v5.x) * w5f;
            acc1.z += bf_lo(v5.y) * w5f; acc1.w += bf_hi(v5.y) * w5f;
            acc2.x += bf_lo(v6.x) * w6f; acc2.y += bf_hi(v6.x) * w6f;
            acc2.z += bf_lo(v6.y) * w6f; acc2.w += bf_hi(v6.y) * w6f;
            acc3.x += bf_lo(v7.x) * w7f; acc3.y += bf_hi(v7.x) * w7f;
            acc3.z += bf_lo(v7.y) * w7f; acc3.w += bf_hi(v7.y) * w7f;
        }
        for (; j + 16 <= take; j += 16) {
            int i0 = j + grp, i1 = j + 4 + grp, i2 = j + 8 + grp, i3 = j + 12 + grp;
            int   s0 = __shfl(es, i0); float w0f = __shfl(ew, i0);
            int   s1 = __shfl(es, i1); float w1f = __shfl(ew, i1);
            int   s2 = __shfl(es, i2); float w2f = __shfl(ew, i2);
            int   s3 = __shfl(es, i3); float w3f = __shfl(ew, i3);
            uint2 v0 = tbl[(size_t)s0 * 16 + lc];
            uint2 v1 = tbl[(size_t)s1 * 16 + lc];
            uint2 v2 = tbl[(size_t)s2 * 16 + lc];
            uint2 v3 = tbl[(size_t)s3 * 16 + lc];
            acc0.x += bf_lo(v0.x) * w0f; acc0.y += bf_hi(v0.x) * w0f;
            acc0.z += bf_lo(v0.y) * w0f; acc0.w += bf_hi(v0.y) * w0f;
            acc1.x += bf_lo(v1.x) * w1f; acc1.y += bf_hi(v1.x) * w1f;
            acc1.z += bf_lo(v1.y) * w1f; acc1.w += bf_hi(v1.y) * w1f;
            acc2.x += bf_lo(v2.x) * w2f; acc2.y += bf_hi(v2.x) * w2f;
            acc2.z += bf_lo(v2.y) * w2f; acc2.w += bf_hi(v2.y) * w2f;
            acc3.x += bf_lo(v3.x) * w3f; acc3.y += bf_hi(v3.x) * w3f;
            acc3.z += bf_lo(v3.y) * w3f; acc3.w += bf_hi(v3.y) * w3f;
        }
        for (; j < take; j += 4) {
            int i0 = j + grp;            // may hit a sentinel lane (w=0) — safe
            int   s0 = __shfl(es, i0); float w0f = __shfl(ew, i0);
            uint2 v0 = tbl[(size_t)s0 * 16 + lc];
            acc0.x += bf_lo(v0.x) * w0f; acc0.y += bf_hi(v0.x) * w0f;
            acc0.z += bf_lo(v0.y) * w0f; acc0.w += bf_hi(v0.y) * w0f;
        }
    }
    acc0.x += acc1.x + acc2.x + acc3.x;
    acc0.y += acc1.y + acc2.y + acc3.y;
    acc0.z += acc1.z + acc2.z + acc3.z;
    acc0.w += acc1.w + acc2.w + acc3.w;
    acc0.x += __shfl_xor(acc0.x, 16); acc0.y += __shfl_xor(acc0.y, 16);
    acc0.z += __shfl_xor(acc0.z, 16); acc0.w += __shfl_xor(acc0.w, 16);
    acc0.x += __shfl_xor(acc0.x, 32); acc0.y += __shfl_xor(acc0.y, 32);
    acc0.z += __shfl_xor(acc0.z, 32); acc0.w += __shfl_xor(acc0.w, 32);
    if (lane < 16)
        nt_store4(acc0, &out[(size_t)node * 128 + colbase + c0]);
}

// ---------------- agg half, 32 cols: eight 8-lane groups, 8 edges/iter, 8-deep ----------------
// tbl rows are 8 uint2 (32 bf16 cols, one 64B line). Table 3.2MB -> L2-resident.
__global__ __launch_bounds__(256) void k_aggh32(const uint2* __restrict__ tbl, const int* __restrict__ esrc,
                                                const int* __restrict__ off, const int* __restrict__ deg,
                                                const float* __restrict__ dinv, const float* __restrict__ b,
                                                float* __restrict__ out, int N, int colbase) {
    const int node = blockIdx.x * 4 + (threadIdx.x >> 6);
    if (node >= N) return;
    const int lane = threadIdx.x & 63;
    const int grp  = lane >> 3;          // 0..7
    const int lc   = lane & 7;           // uint2 index within row
    const int c0   = lc << 2;            // first of 4 cols

    const float di = dinv[node];
    float4 acc0 = {0,0,0,0}, acc1 = {0,0,0,0}, acc2 = {0,0,0,0}, acc3 = {0,0,0,0};
    if (grp == 0) {
        float w0 = di * di;
        uint2  sv = tbl[(size_t)node * 8 + lc];
        float4 bb = *(const float4*)&b[colbase + c0];
        acc0.x = bb.x + bf_lo(sv.x) * w0; acc0.y = bb.y + bf_hi(sv.x) * w0;
        acc0.z = bb.z + bf_lo(sv.y) * w0; acc0.w = bb.w + bf_hi(sv.y) * w0;
    }

    const int base = off[node];
    const int cnt  = deg[node] - 1;
    for (int p0 = 0; p0 < cnt; p0 += 64) {
        int   es = 0;
        float ew = 0.f;
        if (p0 + lane < cnt) {
            es = __builtin_nontemporal_load(&esrc[base + p0 + lane]);
            ew = dinv[es] * di;
        }
        const int take = min(64, cnt - p0);
        int j = 0;
        for (; j + 64 <= take; j += 64) {   // 8 gathers in flight per group
            int i0 = j + grp,      i1 = j + 8 + grp,  i2 = j + 16 + grp, i3 = j + 24 + grp;
            int i4 = j + 32 + grp, i5 = j + 40 + grp, i6 = j + 48 + grp, i7 = j + 56 + grp;
            int   s0 = __shfl(es, i0); float w0f = __shfl(ew, i0);
            int   s1 = __shfl(es, i1); float w1f = __shfl(ew, i1);
            int   s2 = __shfl(es, i2); float w2f = __shfl(ew, i2);
            int   s3 = __shfl(es, i3); float w3f = __shfl(ew, i3);
            int   s4 = __shfl(es, i4); float w4f = __shfl(ew, i4);
            int   s5 = __shfl(es, i5); float w5f = __shfl(ew, i5);
            int   s6 = __shfl(es, i6); float w6f = __shfl(ew, i6);
            int   s7 = __shfl(es, i7); float w7f = __shfl(ew, i7);
            uint2 v0 = tbl[(size_t)s0 * 8 + lc];
            uint2 v1 = tbl[(size_t)s1 * 8 + lc];
            uint2 v2 = tbl[(size_t)s2 * 8 + lc];
            uint2 v3 = tbl[(size_t)s3 * 8 + lc];
            uint2 v4 = tbl[(size_t)s4 * 8 + lc];
            uint2 v5 = tbl[(size_t)s5 * 8 + lc];
            uint2 v6 = tbl[(size_t)s6 * 8 + lc];
            uint2 v7 = tbl[(size_t)s7 * 8 + lc];
            acc0.x += bf_lo(v0.x) * w0f; acc0.y += bf_hi(v0.x) * w0f;
            acc0.z += bf_lo(v0.y) * w0f; acc0.w += bf_hi(v0.y) * w0f;
            acc1.x += bf_lo(v1.x) * w1f; acc1.y += bf_hi(v1.x) * w1f;
            acc1.z += bf_lo(v1.y) * w1f; acc1.w += bf_hi(v1.y) * w1f;
            acc2.x += bf_lo(v2.x) * w2f; acc2.y += bf_hi(v2.x) * w2f;
            acc2.z += bf_lo(v2.y) * w2f; acc2.w += bf_hi(v2.y) * w2f;
            acc3.x += bf_lo(v3.x) * w3f; acc3.y += bf_hi(v3.x) * w3f;
            acc3.z += bf_lo(v3.y) * w3f; acc3.w += bf_hi(v3.y) * w3f;
            acc0.x += bf_lo(v4.x) * w4f; acc0.y += bf_hi(v4.x) * w4f;
            acc0.z += bf_lo(v4.y) * w4f; acc0.w += bf_hi(v4.y) * w4f;
            acc1.x += bf_lo(v5.x) * w5f; acc1.y += bf_hi(v5.x) * w5f;
            acc1.z += bf_lo(v5.y) * w5f; acc1.w += bf_hi(v5.y) * w5f;
            acc2.x += bf_lo(v6.x) * w6f; acc2.y += bf_hi(v6.x) * w6f;
            acc2.z += bf_lo(v6.y) * w6f; acc2.w += bf_hi(v6.y) * w6f;
            acc3.x += bf_lo(v7.x) * w7f; acc3.y += bf_hi(v7.x) * w7f;
            acc3.z += bf_lo(v7.y) * w7f; acc3.w += bf_hi(v7.y) * w7f;
        }
        for (; j + 32 <= take; j += 32) {
            int i0 = j + grp, i1 = j + 8 + grp, i2 = j + 16 + grp, i3 = j + 24 + grp;
            int   s0 = __shfl(es, i0); float w0f = __shfl(ew, i0);
            int   s1 = __shfl(es, i1); float w1f = __shfl(ew, i1);
            int   s2 = __shfl(es, i2); float w2f = __shfl(ew, i2);
            int   s3 = __shfl(es, i3); float w3f = __shfl(ew, i3);
            uint2 v0 = tbl[(size_t)s0 * 8 + lc];
            uint2 v1 = tbl[(size_t)s1 * 8 + lc];
            uint2 v2 = tbl[(size_t)s2 * 8 + lc];
            uint2 v3 = tbl[(size_t)s3 * 8 + lc];
            acc0.x += bf_lo(v0.x) * w0f; acc0.y += bf_hi(v0.x) * w0f;
            acc0.z += bf_lo(v0.y) * w0f; acc0.w += bf_hi(v0.y) * w0f;
            acc1.x += bf_lo(v1.x) * w1f; acc1.y += bf_hi(v1.x) * w1f;
            acc1.z += bf_lo(v1.y) * w1f; acc1.w += bf_hi(v1.y) * w1f;
            acc2.x += bf_lo(v2.x) * w2f; acc2.y += bf_hi(v2.x) * w2f;
            acc2.z += bf_lo(v2.y) * w2f; acc2.w += bf_hi(v2.y) * w2f;
            acc3.x += bf_lo(v3.x) * w3f; acc3.y += bf_hi(v3.x) * w3f;
            acc3.z += bf_lo(v3.y) * w3f; acc3.w += bf_hi(v3.y) * w3f;
        }
        for (; j < take; j += 8) {
            int i0 = j + grp;            // may hit a sentinel lane (w=0) — safe
            int   s0 = __shfl(es, i0); float w0f = __shfl(ew, i0);
            uint2 v0 = tbl[(size_t)s0 * 8 + lc];
            acc0.x += bf_lo(v0.x) * w0f; acc0.y += bf_hi(v0.x) * w0f;
            acc0.z += bf_lo(v0.y) * w0f; acc0.w += bf_hi(v0.y) * w0f;
        }
    }
    acc0.x += acc1.x + acc2.x + acc3.x;
    acc0.y += acc1.y + acc2.y + acc3.y;
    acc0.z += acc1.z + acc2.z + acc3.z;
    acc0.w += acc1.w + acc2.w + acc3.w;
    acc0.x += __shfl_xor(acc0.x, 8);  acc0.y += __shfl_xor(acc0.y, 8);
    acc0.z += __shfl_xor(acc0.z, 8);  acc0.w += __shfl_xor(acc0.w, 8);
    acc0.x += __shfl_xor(acc0.x, 16); acc0.y += __shfl_xor(acc0.y, 16);
    acc0.z += __shfl_xor(acc0.z, 16); acc0.w += __shfl_xor(acc0.w, 16);
    acc0.x += __shfl_xor(acc0.x, 32); acc0.y += __shfl_xor(acc0.y, 32);
    acc0.z += __shfl_xor(acc0.z, 32); acc0.w += __shfl_xor(acc0.w, 32);
    if (lane < 8)
        nt_store4(acc0, &out[(size_t)node * 64 + colbase + c0]);
}

extern "C" void kernel_launch(void* const* d_in, const int* in_sizes, int n_in,
                              void* d_out, int out_size, void* d_ws, size_t ws_size,
                              hipStream_t stream) {
    const float* x  = (const float*)d_in[0];
    const int*   ei = (const int*)  d_in[1];
    const float* W1 = (const float*)d_in[2];
    const float* b1 = (const float*)d_in[3];
    const float* W2 = (const float*)d_in[4];
    const float* b2 = (const float*)d_in[5];
    float* out = (float*)d_out;

    const int N = in_sizes[0] / 128;   // 50000
    const int E = in_sizes[1] / 2;     // 1600000
    const int* src = ei;
    const int* dst = ei + E;
    const int NBUCK = (N + 127) / 128;        // 391 (assumes <= 512)
    const int NA    = (E + ACHUNK - 1) / ACHUNK;
    const int NG    = (N + 63) / 64;          // gemm blocks (782)
    const int NAGG  = (N + 3) / 4;            // agg blocks

    // workspace layout:
    // deg[N] | dinv[N] | off[N] | bstart[512] | bcnt[512] | bcur[512]
    // | esrc[E] int | xwbA[N*64] bf16 | xwbB[N*64] bf16
    // | out1[N*128] f32 (aliases tmp[E] int2) | hwbA[N*32] | hwbB[N*32]
    char* w = (char*)d_ws;
    int*            deg     = (int*)w;        w += (size_t)N * 4;
    float*          dinv    = (float*)w;      w += (size_t)N * 4;
    int*            off     = (int*)w;        w += (size_t)N * 4;
    int*            bstart  = (int*)w;        w += 512 * 4;
    int*            bcnt    = (int*)w;        w += 512 * 4;
    int*            bcur    = (int*)w;        w += 512 * 4;
    int*            esrc    = (int*)w;        w += (size_t)E * 4;
    unsigned short* xwbA    = (unsigned short*)w;  w += (size_t)N * 64 * 2;
    unsigned short* xwbB    = (unsigned short*)w;  w += (size_t)N * 64 * 2;
    float*          out1    = (float*)w;      w += (size_t)N * 128 * 4;
    unsigned short* hwbA    = (unsigned short*)w;  w += (size_t)N * 32 * 2;
    unsigned short* hwbB    = (unsigned short*)w;
    int2*           tmp     = (int2*)out1;    // tmp dead before agg writes out1

    // --- graph preprocessing (every call; deterministic workload) ---
    k_zero512 <<<1, 512, 0, stream>>>(bcnt);
    k_histA   <<<NA, 256, 0, stream>>>(dst, bcnt, E, NBUCK);
    k_bscan   <<<1, 512, 0, stream>>>(bcnt, bstart, bcur);
    k_passA   <<<NA, 256, 0, stream>>>(src, dst, bcur, tmp, E, NBUCK);
    k_passB   <<<NBUCK, 256, 0, stream>>>(tmp, bstart, bcnt, deg, dinv, off, esrc, N);

    // --- layer 1 ---
    k_gemm1 <<<NG, 256, 0, stream>>>(x, W1, xwbA, xwbB, N);
    k_aggh64<<<NAGG, 256, 0, stream>>>((const uint2*)xwbA, esrc, off, deg, dinv, b1, out1, N, 0);
    k_aggh64<<<NAGG, 256, 0, stream>>>((const uint2*)xwbB, esrc, off, deg, dinv, b1, out1, N, 64);

    // --- layer 2 ---
    k_gemm2 <<<NG, 256, 0, stream>>>(out1, W2, hwbA, hwbB, N);
    k_aggh32<<<NAGG, 256, 0, stream>>>((const uint2*)hwbA, esrc, off, deg, dinv, b2, out, N, 0);
    k_aggh32<<<NAGG, 256, 0, stream>>>((const uint2*)hwbB, esrc, off, deg, dinv, b2, out, N, 32);
}

// Round 15
// 205.770 us; speedup vs baseline: 1.2129x; 1.2129x over previous
//
#include <hip/hip_runtime.h>
#include <cstddef>

#define MAXB 512      // max coarse buckets (N<=65536 at 128 nodes/bucket)
#define BSHIFT 7      // 128 dst nodes per bucket
#define ACHUNK 8192   // edges per passA/histA block

typedef __attribute__((ext_vector_type(8))) short short8;
typedef __attribute__((ext_vector_type(4))) float f32x4;

// ---- bf16 pack/unpack helpers (RNE) ----
__device__ inline unsigned pack_bf16x2(float a, float b) {
    unsigned ua = __float_as_uint(a), ub = __float_as_uint(b);
    ua = (ua + 0x7FFFu + ((ua >> 16) & 1u)) >> 16;
    ub = (ub + 0x7FFFu + ((ub >> 16) & 1u)) >> 16;
    return ua | (ub << 16);
}
__device__ inline unsigned short bf16rne(float f) {
    unsigned u = __float_as_uint(f);
    return (unsigned short)((u + 0x7FFFu + ((u >> 16) & 1u)) >> 16);
}
__device__ inline float bf_lo(unsigned u) { return __uint_as_float(u << 16); }
__device__ inline float bf_hi(unsigned u) { return __uint_as_float(u & 0xFFFF0000u); }

__device__ inline void nt_store4(const float4& v, float* p) {
    f32x4 t = { v.x, v.y, v.z, v.w };
    __builtin_nontemporal_store(t, (f32x4*)p);
}

// ---------------- zero the bucket-count table ----------------
__global__ __launch_bounds__(512) void k_zero512(int* __restrict__ p) {
    p[threadIdx.x] = 0;
}

// ---------------- histA: per-bucket edge counts; caches per-block histograms ----------------
__global__ __launch_bounds__(256) void k_histA(const int* __restrict__ dst, int* __restrict__ bcnt,
                                               int* __restrict__ blkhist, int E, int nbuck) {
    __shared__ int hist[MAXB];
    const int tid = threadIdx.x;
    const int e0  = blockIdx.x * ACHUNK;
    const int e1  = min(e0 + ACHUNK, E);
    for (int i = tid; i < nbuck; i += 256) hist[i] = 0;
    __syncthreads();
    for (int e = e0 + tid; e < e1; e += 256)
        atomicAdd(&hist[dst[e] >> BSHIFT], 1);
    __syncthreads();
    int* bh = blkhist + (size_t)blockIdx.x * MAXB;
    for (int i = tid; i < nbuck; i += 256) {
        int c = hist[i];
        bh[i] = c;                         // cached for passA (coalesced write)
        if (c) atomicAdd(&bcnt[i], c);
    }
}

// ---------------- bscan: exclusive scan of bcnt -> bstart; bcur = bstart ----------------
__global__ __launch_bounds__(512) void k_bscan(const int* __restrict__ bcnt, int* __restrict__ bstart,
                                               int* __restrict__ bcur) {
    __shared__ int sh[512];
    const int t = threadIdx.x;
    int v = bcnt[t];
    sh[t] = v;
    __syncthreads();
    for (int d = 1; d < 512; d <<= 1) {
        int u = (t >= d) ? sh[t - d] : 0;
        __syncthreads();
        sh[t] += u;
        __syncthreads();
    }
    int ex = sh[t] - v;
    bstart[t] = ex;
    bcur[t]   = ex;
}

// ---------------- pass A: bucket-run scatter using cached histograms ----------------
__global__ __launch_bounds__(256) void k_passA(const int* __restrict__ src, const int* __restrict__ dst,
                                               const int* __restrict__ blkhist, int* __restrict__ bcur,
                                               int2* __restrict__ tmp, int E, int nbuck) {
    __shared__ int cur[MAXB];
    __shared__ int gbase[MAXB];
    const int tid = threadIdx.x;
    const int e0  = blockIdx.x * ACHUNK;
    const int e1  = min(e0 + ACHUNK, E);
    const int* bh = blkhist + (size_t)blockIdx.x * MAXB;
    for (int i = tid; i < nbuck; i += 256) {
        int c = bh[i];
        gbase[i] = c ? atomicAdd(&bcur[i], c) : 0;
        cur[i] = 0;
    }
    __syncthreads();
    for (int e = e0 + tid; e < e1; e += 256) {
        int d = dst[e];
        int b = d >> BSHIFT;
        int slot = atomicAdd(&cur[b], 1);
        tmp[gbase[b] + slot] = make_int2(src[e], d);
    }
}

// ---------------- pass B: derive deg/dinv/off + exact placement ----------------
__global__ __launch_bounds__(256) void k_passB(const int2* __restrict__ tmp, const int* __restrict__ bstart,
                                               const int* __restrict__ bcnt, int* __restrict__ deg,
                                               float* __restrict__ dinv, int* __restrict__ off,
                                               int* __restrict__ esrc, int N) {
    __shared__ int cnt[1 << BSHIFT];
    __shared__ int loff[1 << BSHIFT];
    __shared__ int cur[1 << BSHIFT];
    const int b     = blockIdx.x;
    const int tid   = threadIdx.x;
    const int node0 = b << BSHIFT;
    const int base  = bstart[b];
    const int cntB  = bcnt[b];

    if (tid < 128) cnt[tid] = 0;
    __syncthreads();
    for (int i = tid; i < cntB; i += 256)
        atomicAdd(&cnt[tmp[base + i].y - node0], 1);
    __syncthreads();
    if (tid < 128) loff[tid] = cnt[tid];
    __syncthreads();
    for (int d = 1; d < 128; d <<= 1) {
        int u = (tid >= d && tid < 128) ? loff[tid - d] : 0;
        __syncthreads();
        if (tid < 128) loff[tid] += u;
        __syncthreads();
    }
    if (tid < 128) {
        int c  = cnt[tid];
        int ex = loff[tid] - c;            // exclusive scan
        cur[tid] = ex;
        if (node0 + tid < N) {
            deg [node0 + tid] = c + 1;     // +1 self-loop
            dinv[node0 + tid] = rsqrtf((float)(c + 1));
            off [node0 + tid] = base + ex;
        }
    }
    __syncthreads();
    for (int i = tid; i < cntB; i += 256) {
        int2 ent = tmp[base + i];
        int  pos = atomicAdd(&cur[ent.y - node0], 1);
        esrc[base + pos] = ent.x;
    }
}

// ---------------- GEMM1 (MFMA): xwb[M,128](bf16) = x[M,128] @ W[128,128] ----------------
__global__ __launch_bounds__(256) void k_gemm1(const float* __restrict__ x, const float* __restrict__ W,
                                               unsigned short* __restrict__ xwb, int M) {
    __shared__ unsigned short Wt[128 * 144];
    __shared__ unsigned short outS[64 * 128];
    const int tid  = threadIdx.x;
    const int row0 = blockIdx.x * 64;

    for (int i = tid; i < 128 * 128; i += 256) {
        int k = i >> 7, col = i & 127;
        Wt[col * 144 + k] = bf16rne(W[i]);
    }
    __syncthreads();

    const int w  = tid >> 6, l = tid & 63;
    const int lr = l & 15,  kg = l >> 4;
    const int row = row0 + w * 16 + lr;

    f32x4 zero4 = {0.f, 0.f, 0.f, 0.f};
    f32x4 acc[8];
#pragma unroll
    for (int ct = 0; ct < 8; ++ct) acc[ct] = zero4;

#pragma unroll
    for (int ks = 0; ks < 4; ++ks) {
        uint4 aw = make_uint4(0u, 0u, 0u, 0u);
        if (row < M) {
            const float* ap = x + (size_t)row * 128 + ks * 32 + kg * 8;
            float4 u = *(const float4*)ap;
            float4 v = *(const float4*)(ap + 4);
            aw = make_uint4(pack_bf16x2(u.x, u.y), pack_bf16x2(u.z, u.w),
                            pack_bf16x2(v.x, v.y), pack_bf16x2(v.z, v.w));
        }
        short8 afrag = *(short8*)&aw;
#pragma unroll
        for (int ct = 0; ct < 8; ++ct) {
            short8 bfrag = *(const short8*)&Wt[(ct * 16 + lr) * 144 + ks * 32 + kg * 8];
            acc[ct] = __builtin_amdgcn_mfma_f32_16x16x32_bf16(afrag, bfrag, acc[ct], 0, 0, 0);
        }
    }

#pragma unroll
    for (int ct = 0; ct < 8; ++ct)
#pragma unroll
        for (int q = 0; q < 4; ++q)
            outS[(w * 16 + kg * 4 + q) * 128 + ct * 16 + lr] = bf16rne(acc[ct][q]);
    __syncthreads();

    // 64 rows x 256B = 1024 uint4
    for (int i = 0; i < 4; ++i) {
        int idx = i * 256 + tid;
        int r   = idx >> 4;                    // 16 uint4 per row
        if (row0 + r < M)
            ((uint4*)xwb)[(size_t)row0 * 16 + idx] = ((const uint4*)outS)[idx];
    }
}

// ---------------- GEMM2 (MFMA): hwb[M,64](bf16) = relu(h[M,128]) @ W[128,64] ----------------
__global__ __launch_bounds__(256) void k_gemm2(const float* __restrict__ h_in, const float* __restrict__ W,
                                               unsigned short* __restrict__ hwb, int M) {
    __shared__ unsigned short Wt[64 * 144];
    __shared__ unsigned short outS[64 * 64];
    const int tid  = threadIdx.x;
    const int row0 = blockIdx.x * 64;

    for (int i = tid; i < 128 * 64; i += 256) {
        int k = i >> 6, col = i & 63;
        Wt[col * 144 + k] = bf16rne(W[i]);
    }
    __syncthreads();

    const int w  = tid >> 6, l = tid & 63;
    const int lr = l & 15,  kg = l >> 4;
    const int row = row0 + w * 16 + lr;

    f32x4 zero4 = {0.f, 0.f, 0.f, 0.f};
    f32x4 acc[4];
#pragma unroll
    for (int ct = 0; ct < 4; ++ct) acc[ct] = zero4;

#pragma unroll
    for (int ks = 0; ks < 4; ++ks) {
        uint4 aw = make_uint4(0u, 0u, 0u, 0u);
        if (row < M) {
            const float* ap = h_in + (size_t)row * 128 + ks * 32 + kg * 8;
            float4 u = *(const float4*)ap;
            float4 v = *(const float4*)(ap + 4);
            u.x = fmaxf(u.x, 0.f); u.y = fmaxf(u.y, 0.f); u.z = fmaxf(u.z, 0.f); u.w = fmaxf(u.w, 0.f);
            v.x = fmaxf(v.x, 0.f); v.y = fmaxf(v.y, 0.f); v.z = fmaxf(v.z, 0.f); v.w = fmaxf(v.w, 0.f);
            aw = make_uint4(pack_bf16x2(u.x, u.y), pack_bf16x2(u.z, u.w),
                            pack_bf16x2(v.x, v.y), pack_bf16x2(v.z, v.w));
        }
        short8 afrag = *(short8*)&aw;
#pragma unroll
        for (int ct = 0; ct < 4; ++ct) {
            short8 bfrag = *(const short8*)&Wt[(ct * 16 + lr) * 144 + ks * 32 + kg * 8];
            acc[ct] = __builtin_amdgcn_mfma_f32_16x16x32_bf16(afrag, bfrag, acc[ct], 0, 0, 0);
        }
    }

#pragma unroll
    for (int ct = 0; ct < 4; ++ct)
#pragma unroll
        for (int q = 0; q < 4; ++q)
            outS[(w * 16 + kg * 4 + q) * 64 + ct * 16 + lr] = bf16rne(acc[ct][q]);
    __syncthreads();

    // 64 rows x 128B = 512 uint4
    for (int i = 0; i < 2; ++i) {
        int idx = i * 256 + tid;
        int r   = idx >> 3;                    // 8 uint4 per row
        if (row0 + r < M)
            ((uint4*)hwb)[(size_t)row0 * 8 + idx] = ((const uint4*)outS)[idx];
    }
}

// ---------------- pull aggregation, layer1 (bf16 gather, 8-deep MLP) ----------------
__global__ __launch_bounds__(256) void k_agg1(const uint2* __restrict__ xwb, const int* __restrict__ esrc,
                                              const int* __restrict__ off, const int* __restrict__ deg,
                                              const float* __restrict__ dinv, const float* __restrict__ b,
                                              float* __restrict__ out1, int N) {
    const int node = blockIdx.x * 4 + (threadIdx.x >> 6);
    if (node >= N) return;
    const int lane = threadIdx.x & 63;
    const int half = lane >> 5;          // 0 or 1
    const int lc   = lane & 31;          // uint2 index within row
    const int c0   = lc << 2;            // first of 4 cols

    const float di = dinv[node];
    float4 acc0 = {0,0,0,0}, acc1 = {0,0,0,0}, acc2 = {0,0,0,0}, acc3 = {0,0,0,0};
    if (half == 0) {                     // self-loop + bias on half 0 only
        float w0 = di * di;
        uint2  sv = xwb[(size_t)node * 32 + lc];
        float4 bb = *(const float4*)&b[c0];
        acc0.x = bb.x + bf_lo(sv.x) * w0; acc0.y = bb.y + bf_hi(sv.x) * w0;
        acc0.z = bb.z + bf_lo(sv.y) * w0; acc0.w = bb.w + bf_hi(sv.y) * w0;
    }

    const int base = off[node];
    const int cnt  = deg[node] - 1;      // real (non-self) in-edges
    for (int p0 = 0; p0 < cnt; p0 += 64) {
        int   es = 0;                    // sentinel: row 0
        float ew = 0.f;                  // sentinel: weight 0
        if (p0 + lane < cnt) {
            es = __builtin_nontemporal_load(&esrc[base + p0 + lane]);
            ew = dinv[es] * di;
        }
        const int take = min(64, cnt - p0);
        int j = 0;
        for (; j + 16 <= take; j += 16) {   // 8 gathers in flight per half
            int i0 = j + half,      i1 = j + 2 + half,  i2 = j + 4 + half,  i3 = j + 6 + half;
            int i4 = j + 8 + half,  i5 = j + 10 + half, i6 = j + 12 + half, i7 = j + 14 + half;
            int   s0 = __shfl(es, i0); float w0f = __shfl(ew, i0);
            int   s1 = __shfl(es, i1); float w1f = __shfl(ew, i1);
            int   s2 = __shfl(es, i2); float w2f = __shfl(ew, i2);
            int   s3 = __shfl(es, i3); float w3f = __shfl(ew, i3);
            int   s4 = __shfl(es, i4); float w4f = __shfl(ew, i4);
            int   s5 = __shfl(es, i5); float w5f = __shfl(ew, i5);
            int   s6 = __shfl(es, i6); float w6f = __shfl(ew, i6);
            int   s7 = __shfl(es, i7); float w7f = __shfl(ew, i7);
            uint2 v0 = xwb[(size_t)s0 * 32 + lc];
            uint2 v1 = xwb[(size_t)s1 * 32 + lc];
            uint2 v2 = xwb[(size_t)s2 * 32 + lc];
            uint2 v3 = xwb[(size_t)s3 * 32 + lc];
            uint2 v4 = xwb[(size_t)s4 * 32 + lc];
            uint2 v5 = xwb[(size_t)s5 * 32 + lc];
            uint2 v6 = xwb[(size_t)s6 * 32 + lc];
            uint2 v7 = xwb[(size_t)s7 * 32 + lc];
            acc0.x += bf_lo(v0.x) * w0f; acc0.y += bf_hi(v0.x) * w0f;
            acc0.z += bf_lo(v0.y) * w0f; acc0.w += bf_hi(v0.y) * w0f;
            acc1.x += bf_lo(v1.x) * w1f; acc1.y += bf_hi(v1.x) * w1f;
            acc1.z += bf_lo(v1.y) * w1f; acc1.w += bf_hi(v1.y) * w1f;
            acc2.x += bf_lo(v2.x) * w2f; acc2.y += bf_hi(v2.x) * w2f;
            acc2.z += bf_lo(v2.y) * w2f; acc2.w += bf_hi(v2.y) * w2f;
            acc3.x += bf_lo(v3.x) * w3f; acc3.y += bf_hi(v3.x) * w3f;
            acc3.z += bf_lo(v3.y) * w3f; acc3.w += bf_hi(v3.y) * w3f;
            acc0.x += bf_lo(v4.x) * w4f; acc0.y += bf_hi(v4.x) * w4f;
            acc0.z += bf_lo(v4.y) * w4f; acc0.w += bf_hi(v4.y) * w4f;
            acc1.x += bf_lo(v5.x) * w5f; acc1.y += bf_hi(v5.x) * w5f;
            acc1.z += bf_lo(v5.y) * w5f; acc1.w += bf_hi(v5.y) * w5f;
            acc2.x += bf_lo(v6.x) * w6f; acc2.y += bf_hi(v6.x) * w6f;
            acc2.z += bf_lo(v6.y) * w6f; acc2.w += bf_hi(v6.y) * w6f;
            acc3.x += bf_lo(v7.x) * w7f; acc3.y += bf_hi(v7.x) * w7f;
            acc3.z += bf_lo(v7.y) * w7f; acc3.w += bf_hi(v7.y) * w7f;
        }
        for (; j + 8 <= take; j += 8) {
            int i0 = j + half, i1 = j + 2 + half, i2 = j + 4 + half, i3 = j + 6 + half;
            int   s0 = __shfl(es, i0); float w0f = __shfl(ew, i0);
            int   s1 = __shfl(es, i1); float w1f = __shfl(ew, i1);
            int   s2 = __shfl(es, i2); float w2f = __shfl(ew, i2);
            int   s3 = __shfl(es, i3); float w3f = __shfl(ew, i3);
            uint2 v0 = xwb[(size_t)s0 * 32 + lc];
            uint2 v1 = xwb[(size_t)s1 * 32 + lc];
            uint2 v2 = xwb[(size_t)s2 * 32 + lc];
            uint2 v3 = xwb[(size_t)s3 * 32 + lc];
            acc0.x += bf_lo(v0.x) * w0f; acc0.y += bf_hi(v0.x) * w0f;
            acc0.z += bf_lo(v0.y) * w0f; acc0.w += bf_hi(v0.y) * w0f;
            acc1.x += bf_lo(v1.x) * w1f; acc1.y += bf_hi(v1.x) * w1f;
            acc1.z += bf_lo(v1.y) * w1f; acc1.w += bf_hi(v1.y) * w1f;
            acc2.x += bf_lo(v2.x) * w2f; acc2.y += bf_hi(v2.x) * w2f;
            acc2.z += bf_lo(v2.y) * w2f; acc2.w += bf_hi(v2.y) * w2f;
            acc3.x += bf_lo(v3.x) * w3f; acc3.y += bf_hi(v3.x) * w3f;
            acc3.z += bf_lo(v3.y) * w3f; acc3.w += bf_hi(v3.y) * w3f;
        }
        for (; j < take; j += 2) {
            int i0 = j + half;           // may hit a sentinel lane (w=0) — safe
            int   s0 = __shfl(es, i0); float w0f = __shfl(ew, i0);
            uint2 v0 = xwb[(size_t)s0 * 32 + lc];
            acc0.x += bf_lo(v0.x) * w0f; acc0.y += bf_hi(v0.x) * w0f;
            acc0.z += bf_lo(v0.y) * w0f; acc0.w += bf_hi(v0.y) * w0f;
        }
    }
    acc0.x += acc1.x + acc2.x + acc3.x;
    acc0.y += acc1.y + acc2.y + acc3.y;
    acc0.z += acc1.z + acc2.z + acc3.z;
    acc0.w += acc1.w + acc2.w + acc3.w;
    acc0.x += __shfl_xor(acc0.x, 32);
    acc0.y += __shfl_xor(acc0.y, 32);
    acc0.z += __shfl_xor(acc0.z, 32);
    acc0.w += __shfl_xor(acc0.w, 32);
    if (half == 0)
        nt_store4(acc0, &out1[(size_t)node * 128 + c0]);
}

// ---------------- pull aggregation, layer2 (bf16 gather, 8-deep MLP) ----------------
__global__ __launch_bounds__(256) void k_agg2(const uint2* __restrict__ hwb, const int* __restrict__ esrc,
                                              const int* __restrict__ off, const int* __restrict__ deg,
                                              const float* __restrict__ dinv, const float* __restrict__ b,
                                              float* __restrict__ out, int N) {
    const int node = blockIdx.x * 4 + (threadIdx.x >> 6);
    if (node >= N) return;
    const int lane = threadIdx.x & 63;
    const int grp  = lane >> 4;          // 0..3
    const int lc   = lane & 15;          // uint2 index within row
    const int c0   = lc << 2;            // first of 4 cols

    const float di = dinv[node];
    float4 acc0 = {0,0,0,0}, acc1 = {0,0,0,0}, acc2 = {0,0,0,0}, acc3 = {0,0,0,0};
    if (grp == 0) {
        float w0 = di * di;
        uint2  sv = hwb[(size_t)node * 16 + lc];
        float4 bb = *(const float4*)&b[c0];
        acc0.x = bb.x + bf_lo(sv.x) * w0; acc0.y = bb.y + bf_hi(sv.x) * w0;
        acc0.z = bb.z + bf_lo(sv.y) * w0; acc0.w = bb.w + bf_hi(sv.y) * w0;
    }

    const int base = off[node];
    const int cnt  = deg[node] - 1;
    for (int p0 = 0; p0 < cnt; p0 += 64) {
        int   es = 0;
        float ew = 0.f;
        if (p0 + lane < cnt) {
            es = __builtin_nontemporal_load(&esrc[base + p0 + lane]);
            ew = dinv[es] * di;
        }
        const int take = min(64, cnt - p0);
        int j = 0;
        for (; j + 32 <= take; j += 32) {   // 8 gathers in flight per group
            int i0 = j + grp,      i1 = j + 4 + grp,  i2 = j + 8 + grp,  i3 = j + 12 + grp;
            int i4 = j + 16 + grp, i5 = j + 20 + grp, i6 = j + 24 + grp, i7 = j + 28 + grp;
            int   s0 = __shfl(es, i0); float w0f = __shfl(ew, i0);
            int   s1 = __shfl(es, i1); float w1f = __shfl(ew, i1);
            int   s2 = __shfl(es, i2); float w2f = __shfl(ew, i2);
            int   s3 = __shfl(es, i3); float w3f = __shfl(ew, i3);
            int   s4 = __shfl(es, i4); float w4f = __shfl(ew, i4);
            int   s5 = __shfl(es, i5); float w5f = __shfl(ew, i5);
            int   s6 = __shfl(es, i6); float w6f = __shfl(ew, i6);
            int   s7 = __shfl(es, i7); float w7f = __shfl(ew, i7);
            uint2 v0 = hwb[(size_t)s0 * 16 + lc];
            uint2 v1 = hwb[(size_t)s1 * 16 + lc];
            uint2 v2 = hwb[(size_t)s2 * 16 + lc];
            uint2 v3 = hwb[(size_t)s3 * 16 + lc];
            uint2 v4 = hwb[(size_t)s4 * 16 + lc];
            uint2 v5 = hwb[(size_t)s5 * 16 + lc];
            uint2 v6 = hwb[(size_t)s6 * 16 + lc];
            uint2 v7 = hwb[(size_t)s7 * 16 + lc];
            acc0.x += bf_lo(v0.x) * w0f; acc0.y += bf_hi(v0.x) * w0f;
            acc0.z += bf_lo(v0.y) * w0f; acc0.w += bf_hi(v0.y) * w0f;
            acc1.x += bf_lo(v1.x) * w1f; acc1.y += bf_hi(v1.x) * w1f;
            acc1.z += bf_lo(v1.y) * w1f; acc1.w += bf_hi(v1.y) * w1f;
            acc2.x += bf_lo(v2.x) * w2f; acc2.y += bf_hi(v2.x) * w2f;
            acc2.z += bf_lo(v2.y) * w2f; acc2.w += bf_hi(v2.y) * w2f;
            acc3.x += bf_lo(v3.x) * w3f; acc3.y += bf_hi(v3.x) * w3f;
            acc3.z += bf_lo(v3.y) * w3f; acc3.w += bf_hi(v3.y) * w3f;
            acc0.x += bf_lo(v4.x) * w4f; acc0.y += bf_hi(v4.x) * w4f;
            acc0.z += bf_lo(v4.y) * w4f; acc0.w += bf_hi(v4.y) * w4f;
            acc1.x += bf_lo(v5.x) * w5f; acc1.y += bf_hi(v5.x) * w5f;
            acc1.z += bf_lo(v5.y) * w5f; acc1.w += bf_hi(v5.y) * w5f;
            acc2.x += bf_lo(v6.x) * w6f; acc2.y += bf_hi(v6.x) * w6f;
            acc2.z += bf_lo(v6.y) * w6f; acc2.w += bf_hi(v6.y) * w6f;
            acc3.x += bf_lo(v7.x) * w7f; acc3.y += bf_hi(v7.x) * w7f;
            acc3.z += bf_lo(v7.y) * w7f; acc3.w += bf_hi(v7.y) * w7f;
        }
        for (; j + 16 <= take; j += 16) {
            int i0 = j + grp, i1 = j + 4 + grp, i2 = j + 8 + grp, i3 = j + 12 + grp;
            int   s0 = __shfl(es, i0); float w0f = __shfl(ew, i0);
            int   s1 = __shfl(es, i1); float w1f = __shfl(ew, i1);
            int   s2 = __shfl(es, i2); float w2f = __shfl(ew, i2);
            int   s3 = __shfl(es, i3); float w3f = __shfl(ew, i3);
            uint2 v0 = hwb[(size_t)s0 * 16 + lc];
            uint2 v1 = hwb[(size_t)s1 * 16 + lc];
            uint2 v2 = hwb[(size_t)s2 * 16 + lc];
            uint2 v3 = hwb[(size_t)s3 * 16 + lc];
            acc0.x += bf_lo(v0.x) * w0f; acc0.y += bf_hi(v0.x) * w0f;
            acc0.z += bf_lo(v0.y) * w0f; acc0.w += bf_hi(v0.y) * w0f;
            acc1.x += bf_lo(v1.x) * w1f; acc1.y += bf_hi(v1.x) * w1f;
            acc1.z += bf_lo(v1.y) * w1f; acc1.w += bf_hi(v1.y) * w1f;
            acc2.x += bf_lo(v2.x) * w2f; acc2.y += bf_hi(v2.x) * w2f;
            acc2.z += bf_lo(v2.y) * w2f; acc2.w += bf_hi(v2.y) * w2f;
            acc3.x += bf_lo(v3.x) * w3f; acc3.y += bf_hi(v3.x) * w3f;
            acc3.z += bf_lo(v3.y) * w3f; acc3.w += bf_hi(v3.y) * w3f;
        }
        for (; j < take; j += 4) {
            int i0 = j + grp;            // may hit a sentinel lane (w=0) — safe
            int   s0 = __shfl(es, i0); float w0f = __shfl(ew, i0);
            uint2 v0 = hwb[(size_t)s0 * 16 + lc];
            acc0.x += bf_lo(v0.x) * w0f; acc0.y += bf_hi(v0.x) * w0f;
            acc0.z += bf_lo(v0.y) * w0f; acc0.w += bf_hi(v0.y) * w0f;
        }
    }
    acc0.x += acc1.x + acc2.x + acc3.x;
    acc0.y += acc1.y + acc2.y + acc3.y;
    acc0.z += acc1.z + acc2.z + acc3.z;
    acc0.w += acc1.w + acc2.w + acc3.w;
    acc0.x += __shfl_xor(acc0.x, 16); acc0.y += __shfl_xor(acc0.y, 16);
    acc0.z += __shfl_xor(acc0.z, 16); acc0.w += __shfl_xor(acc0.w, 16);
    acc0.x += __shfl_xor(acc0.x, 32); acc0.y += __shfl_xor(acc0.y, 32);
    acc0.z += __shfl_xor(acc0.z, 32); acc0.w += __shfl_xor(acc0.w, 32);
    if (lane < 16)
        nt_store4(acc0, &out[(size_t)node * 64 + c0]);
}

extern "C" void kernel_launch(void* const* d_in, const int* in_sizes, int n_in,
                              void* d_out, int out_size, void* d_ws, size_t ws_size,
                              hipStream_t stream) {
    const float* x  = (const float*)d_in[0];
    const int*   ei = (const int*)  d_in[1];
    const float* W1 = (const float*)d_in[2];
    const float* b1 = (const float*)d_in[3];
    const float* W2 = (const float*)d_in[4];
    const float* b2 = (const float*)d_in[5];
    float* out = (float*)d_out;

    const int N = in_sizes[0] / 128;   // 50000
    const int E = in_sizes[1] / 2;     // 1600000
    const int* src = ei;
    const int* dst = ei + E;
    const int NBUCK = (N + 127) / 128;        // 391 (assumes <= 512)
    const int NA    = (E + ACHUNK - 1) / ACHUNK;
    const int NG    = (N + 63) / 64;          // gemm blocks (782)

    // workspace layout:
    // deg[N] | dinv[N] | off[N] | bstart[512] | bcnt[512] | bcur[512] | blkhist[NA*512]
    // | esrc[E] int | xwb[N*128] bf16 | out1[N*128] f32 (aliases tmp[E] int2) | hwb[N*64] bf16
    char* w = (char*)d_ws;
    int*            deg     = (int*)w;        w += (size_t)N * 4;
    float*          dinv    = (float*)w;      w += (size_t)N * 4;
    int*            off     = (int*)w;        w += (size_t)N * 4;
    int*            bstart  = (int*)w;        w += 512 * 4;
    int*            bcnt    = (int*)w;        w += 512 * 4;
    int*            bcur    = (int*)w;        w += 512 * 4;
    int*            blkhist = (int*)w;        w += (size_t)NA * MAXB * 4;
    int*            esrc    = (int*)w;        w += (size_t)E * 4;
    unsigned short* xwb     = (unsigned short*)w;  w += (size_t)N * 128 * 2;
    float*          out1    = (float*)w;      w += (size_t)N * 128 * 4;
    unsigned short* hwb     = (unsigned short*)w;
    int2*           tmp     = (int2*)out1;    // tmp dead before agg1 writes out1

    // --- graph preprocessing (every call; deterministic workload) ---
    k_zero512 <<<1, 512, 0, stream>>>(bcnt);
    k_histA   <<<NA, 256, 0, stream>>>(dst, bcnt, blkhist, E, NBUCK);
    k_bscan   <<<1, 512, 0, stream>>>(bcnt, bstart, bcur);
    k_passA   <<<NA, 256, 0, stream>>>(src, dst, blkhist, bcur, tmp, E, NBUCK);
    k_passB   <<<NBUCK, 256, 0, stream>>>(tmp, bstart, bcnt, deg, dinv, off, esrc, N);

    // --- layer 1 ---
    k_gemm1 <<<NG, 256, 0, stream>>>(x, W1, xwb, N);
    k_agg1  <<<(N + 3) / 4, 256, 0, stream>>>((const uint2*)xwb, esrc, off, deg, dinv, b1, out1, N);

    // --- layer 2 ---
    k_gemm2 <<<NG, 256, 0, stream>>>(out1, W2, hwb, N);
    k_agg2  <<<(N + 3) / 4, 256, 0, stream>>>((const uint2*)hwb, esrc, off, deg, dinv, b2, out, N);
}